// Round 1
// baseline (2480.303 us; speedup 1.0000x reference)
//
#include <hip/hip_runtime.h>

// Persistent-block VRNN: each block owns 16 batch rows for all 16 timesteps.
// All matmuls via v_mfma_f32_16x16x32_bf16; weights pre-converted to bf16
// MFMA-fragment layout in d_ws so weight streaming is fully coalesced.
// h_i-dependent GEMM parts are precomputed once per launch (inside kernel).

typedef __attribute__((ext_vector_type(8))) short short8;
typedef __attribute__((ext_vector_type(4))) float f32x4;

#define Bt 4096
#define Hd 512
#define Fd 256
#define Zd 64
#define Td 16

// workspace offsets in short8 (16B) chunks
#define OFF_WG   0          // gates dyn: K=832 ([z|y_prev|h]), N=2048, KT=26, NT=128
#define OFF_WPH  212992     // h_i gates: K=512, N=2048, KT=16
#define OFF_W1   344064     // K=512 N=256 KT=16 NT=16
#define OFF_W2   360448     // K=256 N=256 KT=8
#define OFF_W3   368640
#define OFF_W4D  376832     // K=1024 ([s|y_prev|y_cur]) N=64 KT=32 NT=4
#define OFF_W4H  385024     // K=512 N=64 KT=16
#define OFF_W7D  389120     // K=768 ([s|y_prev]) N=64 KT=24
#define OFF_W7H  395264     // K=512 N=64 KT=16
#define OFF_W5   399360     // K=64 N=64 KT=2
#define OFF_W6   399872
#define OFF_W8   400384
#define OFF_W9   400896

#define O1 16777216   // mean_all offset in floats
#define O2 20971520   // log_var_all
#define O3 25165824   // z_all

__device__ inline short f2bf(float f) {
  unsigned u = __builtin_bit_cast(unsigned, f);
  unsigned r = (u + 0x7FFFu + ((u >> 16) & 1u)) >> 16;
  return (short)(unsigned short)r;
}
__device__ inline float sigm(float x) { return 1.f / (1.f + __expf(-x)); }
__device__ inline float tanhx(float x) { return 1.f - 2.f / (__expf(2.f * x) + 1.f); }

// Convert f32 weights (row-major [K][N], possibly concatenated from up to 3
// row-ranges) into bf16 MFMA fragment order:
// chunk[((nt*KT+kt)*64+lane)][j] = W[kt*32+(lane>>4)*8+j][nt*16+(lane&15)]
__global__ void conv_frag(const float* s0, int k0, const float* s1, int k1,
                          const float* s2, int k2, int N, short8* dst, int KT,
                          int total) {
  int idx = blockIdx.x * blockDim.x + threadIdx.x;
  if (idx >= total) return;
  int lane = idx & 63;
  int tt = idx >> 6;
  int kt = tt % KT;
  int nt = tt / KT;
  int c = nt * 16 + (lane & 15);
  int kb = kt * 32 + (lane >> 4) * 8;
  short8 v;
#pragma unroll
  for (int j = 0; j < 8; ++j) {
    int kc = kb + j;
    float f;
    if (kc < k0) f = s0[kc * N + c];
    else if (kc < k0 + k1) f = s1[(kc - k0) * N + c];
    else f = s2[(kc - k0 - k1) * N + c];
    v[j] = f2bf(f);
  }
  dst[idx] = v;
}

struct Params {
  const float* h_i; const float* eps_inf; const float* eps_pri;
  const float* b_lstm;
  const float *b1, *b2, *b3, *b4, *b5, *b6, *b7, *b8, *b9;
  const short8 *WG, *WPH, *W1f, *W2f, *W3f, *W4d, *W4h, *W7d, *W7h,
               *W5f, *W6f, *W8f, *W9f;
  float* out;
};

#define A1S 840    // [z(0:64)|y_prev(64:320)|h(320:832)] +8 pad
#define A4S 1032   // [s(0:512)|y_prev(512:768)|y_cur(768:1024)] +8 pad
#define TS  264
#define HZS 72

#define MFMA(a, b, c) __builtin_amdgcn_mfma_f32_16x16x32_bf16((a), (b), (c), 0, 0, 0)

template <int KT>
__device__ inline void dense2(const short* Asrc, int astride, int aoff,
                              const short8* W, const float* bias,
                              int wave, int lane, f32x4& o0, f32x4& o1) {
  int lrow = lane >> 4, lcol = lane & 15;
  float b0 = bias[(wave * 2 + 0) * 16 + lcol];
  float b1 = bias[(wave * 2 + 1) * 16 + lcol];
  o0 = (f32x4){b0, b0, b0, b0};
  o1 = (f32x4){b1, b1, b1, b1};
  for (int kt = 0; kt < KT; ++kt) {
    short8 a = *(const short8*)&Asrc[lcol * astride + aoff + kt * 32 + lrow * 8];
    short8 w0 = W[((wave * 2 + 0) * KT + kt) * 64 + lane];
    short8 w1 = W[((wave * 2 + 1) * KT + kt) * 64 + lane];
    o0 = MFMA(a, w0, o0);
    o1 = MFMA(a, w1, o1);
  }
}

__global__ __launch_bounds__(512, 2) void vrnn_kernel(Params p) {
  __shared__ short A1[16 * A1S];
  __shared__ short A4[16 * A4S];
  __shared__ short T1[16 * TS];
  __shared__ short T2[16 * TS];
  __shared__ short HZi[16 * HZS];
  __shared__ short HZp[16 * HZS];
  __shared__ float Mi[1024], Li[1024], Mp[1024], Lp[1024];

  const int tid = threadIdx.x;
  const int wave = tid >> 6;
  const int lane = tid & 63;
  const int lrow = lane >> 4;
  const int lcol = lane & 15;
  const int rowbase = blockIdx.x * 16;

  f32x4 base[4][4];   // [gate][ct] per-wave gate base (h_i@Wx + b_lstm)
  f32x4 cst[4];       // cell state fragments
  f32x4 base47;       // h_i@W4+b4 (waves 0-3) / h_i@W7+b7 (waves 4-7)

  // ---- init: stage h_i (bf16) into A1.h, zero dynamic slots ----
  for (int i = tid; i < 16 * 512; i += 512) {
    int r = i >> 9, c = i & 511;
    A1[r * A1S + 320 + c] = f2bf(p.h_i[(rowbase + r) * Hd + c]);
  }
  for (int i = tid; i < 16 * 320; i += 512) {
    int r = i / 320, c = i - r * 320;
    A1[r * A1S + c] = 0;
  }
  for (int i = tid; i < 16 * 256; i += 512) {
    int r = i >> 8, c = i & 255;
    A4[r * A4S + 512 + c] = 0;
  }
  __syncthreads();

  // ---- precompute base = h_i @ Wx_h + b_lstm ----
#pragma unroll
  for (int g = 0; g < 4; ++g)
#pragma unroll
    for (int ct = 0; ct < 4; ++ct) {
      float b = p.b_lstm[g * 512 + wave * 64 + ct * 16 + lcol];
      base[g][ct] = (f32x4){b, b, b, b};
    }
  for (int kt = 0; kt < 16; ++kt) {
    short8 a = *(const short8*)&A1[lcol * A1S + 320 + kt * 32 + lrow * 8];
#pragma unroll
    for (int g = 0; g < 4; ++g)
#pragma unroll
      for (int ct = 0; ct < 4; ++ct) {
        int nt = g * 32 + wave * 4 + ct;
        short8 w = p.WPH[(nt * 16 + kt) * 64 + lane];
        base[g][ct] = MFMA(a, w, base[g][ct]);
      }
  }
  // ---- precompute base4 / base7 ----
  {
    const short8* W = (wave < 4) ? p.W4h : p.W7h;
    const float* bb = (wave < 4) ? p.b4 : p.b7;
    int nt = wave & 3;
    float b = bb[nt * 16 + lcol];
    base47 = (f32x4){b, b, b, b};
    for (int kt = 0; kt < 16; ++kt) {
      short8 a = *(const short8*)&A1[lcol * A1S + 320 + kt * 32 + lrow * 8];
      short8 w = W[(nt * 16 + kt) * 64 + lane];
      base47 = MFMA(a, w, base47);
    }
  }
  __syncthreads();
  // zero h (initial LSTM state)
  for (int i = tid; i < 16 * 512; i += 512) {
    int r = i >> 9, c = i & 511;
    A1[r * A1S + 320 + c] = 0;
  }
#pragma unroll
  for (int ct = 0; ct < 4; ++ct) cst[ct] = (f32x4){0.f, 0.f, 0.f, 0.f};
  __syncthreads();

  // ---- time loop ----
  for (int t = 0; t < Td; ++t) {
    // phase 1: gates = [z|y_prev|h] @ WG + base
    f32x4 acc[4][4];
#pragma unroll
    for (int g = 0; g < 4; ++g)
#pragma unroll
      for (int ct = 0; ct < 4; ++ct) acc[g][ct] = base[g][ct];
#pragma unroll 2
    for (int kt = 0; kt < 26; ++kt) {
      short8 a = *(const short8*)&A1[lcol * A1S + kt * 32 + lrow * 8];
#pragma unroll
      for (int g = 0; g < 4; ++g)
#pragma unroll
        for (int ct = 0; ct < 4; ++ct) {
          int nt = g * 32 + wave * 4 + ct;
          short8 w = p.WG[(nt * 26 + kt) * 64 + lane];
          acc[g][ct] = MFMA(a, w, acc[g][ct]);
        }
    }
    __syncthreads();

    // phase 2: LSTM pointwise; write h_new -> A1.h, c_new -> A4.s
#pragma unroll
    for (int ct = 0; ct < 4; ++ct) {
#pragma unroll
      for (int r = 0; r < 4; ++r) {
        float iv = sigm(acc[0][ct][r]);
        float fv = sigm(acc[1][ct][r]);
        float gv = tanhx(acc[2][ct][r]);
        float ov = sigm(acc[3][ct][r]);
        float cn = fv * cst[ct][r] + iv * gv;
        cst[ct][r] = cn;
        float hn = ov * tanhx(cn);
        int row = lrow * 4 + r;
        int col = wave * 64 + ct * 16 + lcol;
        A1[row * A1S + 320 + col] = f2bf(hn);
        A4[row * A4S + col] = f2bf(cn);
      }
    }
    __syncthreads();

    // phase 3: y = relu(relu(relu(h@W1)@W2)@W3)
    {
      f32x4 o0, o1;
      dense2<16>(A1, A1S, 320, p.W1f, p.b1, wave, lane, o0, o1);
#pragma unroll
      for (int r = 0; r < 4; ++r) {
        int row = lrow * 4 + r;
        T1[row * TS + wave * 32 + lcol] = f2bf(fmaxf(o0[r], 0.f));
        T1[row * TS + wave * 32 + 16 + lcol] = f2bf(fmaxf(o1[r], 0.f));
      }
    }
    __syncthreads();
    {
      f32x4 o0, o1;
      dense2<8>(T1, TS, 0, p.W2f, p.b2, wave, lane, o0, o1);
#pragma unroll
      for (int r = 0; r < 4; ++r) {
        int row = lrow * 4 + r;
        T2[row * TS + wave * 32 + lcol] = f2bf(fmaxf(o0[r], 0.f));
        T2[row * TS + wave * 32 + 16 + lcol] = f2bf(fmaxf(o1[r], 0.f));
      }
    }
    __syncthreads();
    {
      f32x4 o0, o1;
      dense2<8>(T2, TS, 0, p.W3f, p.b3, wave, lane, o0, o1);
#pragma unroll
      for (int r = 0; r < 4; ++r) {
        int row = lrow * 4 + r;
        int c0 = wave * 32 + lcol, c1 = wave * 32 + 16 + lcol;
        float v0 = fmaxf(o0[r], 0.f), v1 = fmaxf(o1[r], 0.f);
        A4[row * A4S + 768 + c0] = f2bf(v0);
        A4[row * A4S + 768 + c1] = f2bf(v1);
        p.out[(size_t)(rowbase + row) * 4096 + t * 256 + c0] = v0;
        p.out[(size_t)(rowbase + row) * 4096 + t * 256 + c1] = v1;
      }
    }
    __syncthreads();

    // phase 4: h_z (inf, waves 0-3, K=1024) / h_z_ (pri, waves 4-7, K=768)
    {
      f32x4 hz = base47;
      if (wave < 4) {
        int nt = wave;
        for (int kt = 0; kt < 32; ++kt) {
          short8 a = *(const short8*)&A4[lcol * A4S + kt * 32 + lrow * 8];
          short8 w = p.W4d[(nt * 32 + kt) * 64 + lane];
          hz = MFMA(a, w, hz);
        }
#pragma unroll
        for (int r = 0; r < 4; ++r)
          HZi[(lrow * 4 + r) * HZS + nt * 16 + lcol] = f2bf(fmaxf(hz[r], 0.f));
      } else {
        int nt = wave - 4;
        for (int kt = 0; kt < 24; ++kt) {
          short8 a = *(const short8*)&A4[lcol * A4S + kt * 32 + lrow * 8];
          short8 w = p.W7d[(nt * 24 + kt) * 64 + lane];
          hz = MFMA(a, w, hz);
        }
#pragma unroll
        for (int r = 0; r < 4; ++r)
          HZp[(lrow * 4 + r) * HZS + nt * 16 + lcol] = f2bf(fmaxf(hz[r], 0.f));
      }
    }
    __syncthreads();

    // phase 5: mean/log_var heads (W5,W6 inf; W8,W9 pri), K=64
    {
      int m = wave >> 1;
      const short8* W = (m == 0) ? p.W5f : (m == 1) ? p.W6f : (m == 2) ? p.W8f : p.W9f;
      const float* bb = (m == 0) ? p.b5 : (m == 1) ? p.b6 : (m == 2) ? p.b8 : p.b9;
      const short* As = (wave < 4) ? HZi : HZp;
      int wj = wave & 1;
      float b0 = bb[(wj * 2 + 0) * 16 + lcol];
      float b1 = bb[(wj * 2 + 1) * 16 + lcol];
      f32x4 o0 = (f32x4){b0, b0, b0, b0};
      f32x4 o1 = (f32x4){b1, b1, b1, b1};
#pragma unroll
      for (int kt = 0; kt < 2; ++kt) {
        short8 a = *(const short8*)&As[lcol * HZS + kt * 32 + lrow * 8];
        short8 w0 = W[((wj * 2 + 0) * 2 + kt) * 64 + lane];
        short8 w1 = W[((wj * 2 + 1) * 2 + kt) * 64 + lane];
        o0 = MFMA(a, w0, o0);
        o1 = MFMA(a, w1, o1);
      }
#pragma unroll
      for (int r = 0; r < 4; ++r) {
        int row = lrow * 4 + r;
        int c0 = wj * 32 + lcol, c1 = wj * 32 + 16 + lcol;
        float v0 = fmaxf(o0[r], 0.f), v1 = fmaxf(o1[r], 0.f);
        size_t gb = (size_t)(rowbase + row) * 1024 + t * 64;
        if (m == 0) {
          Mi[row * 64 + c0] = v0; Mi[row * 64 + c1] = v1;
          p.out[O1 + gb + c0] = v0; p.out[O1 + gb + c1] = v1;
        } else if (m == 1) {
          Li[row * 64 + c0] = v0; Li[row * 64 + c1] = v1;
          p.out[O2 + gb + c0] = v0; p.out[O2 + gb + c1] = v1;
        } else if (m == 2) {
          Mp[row * 64 + c0] = v0; Mp[row * 64 + c1] = v1;
        } else {
          Lp[row * 64 + c0] = v0; Lp[row * 64 + c1] = v1;
        }
      }
    }
    __syncthreads();

    // phase 6: z sampling + output + state shuffles
    for (int e = tid; e < 1024; e += 512) {
      int row = e >> 6, col = e & 63;
      int b = rowbase + row;
      float ei = p.eps_inf[((size_t)t * Bt + b) * 64 + col];
      float ep = p.eps_pri[((size_t)t * Bt + b) * 64 + col];
      float zi = Mi[e] + ei * sqrtf(__expf(Li[e]));
      float zp = Mp[e] + ep * sqrtf(__expf(Lp[e]));
      p.out[O3 + ((size_t)(t * 2 + 0) * Bt + b) * 64 + col] = zi;
      p.out[O3 + ((size_t)(t * 2 + 1) * Bt + b) * 64 + col] = zp;
      A1[row * A1S + col] = f2bf(zi);   // z state for next step
    }
    for (int i = tid; i < 16 * 256; i += 512) {
      int r = i >> 8, c = i & 255;
      short v = A4[r * A4S + 768 + c];  // y_cur
      A1[r * A1S + 64 + c] = v;         // -> A1.y_prev
      A4[r * A4S + 512 + c] = v;        // -> A4.y_prev
    }
    __syncthreads();
  }
}

extern "C" void kernel_launch(void* const* d_in, const int* in_sizes, int n_in,
                              void* d_out, int out_size, void* d_ws, size_t ws_size,
                              hipStream_t stream) {
  const float* h_i     = (const float*)d_in[0];
  const float* eps_inf = (const float*)d_in[1];
  const float* eps_pri = (const float*)d_in[2];
  const float* Wx      = (const float*)d_in[3];
  const float* Wh      = (const float*)d_in[4];
  const float* b_lstm  = (const float*)d_in[5];
  const float* W1 = (const float*)d_in[6];  const float* b1 = (const float*)d_in[7];
  const float* W2 = (const float*)d_in[8];  const float* b2 = (const float*)d_in[9];
  const float* W3 = (const float*)d_in[10]; const float* b3 = (const float*)d_in[11];
  const float* W4 = (const float*)d_in[12]; const float* b4 = (const float*)d_in[13];
  const float* W5 = (const float*)d_in[14]; const float* b5 = (const float*)d_in[15];
  const float* W6 = (const float*)d_in[16]; const float* b6 = (const float*)d_in[17];
  const float* W7 = (const float*)d_in[18]; const float* b7 = (const float*)d_in[19];
  const float* W8 = (const float*)d_in[20]; const float* b8 = (const float*)d_in[21];
  const float* W9 = (const float*)d_in[22]; const float* b9 = (const float*)d_in[23];
  short8* ws = (short8*)d_ws;
  const float* nil = nullptr;

  auto cv = [&](const float* s0, int k0, const float* s1, int k1,
                const float* s2, int k2, int N, int off, int KT, int NT) {
    int total = NT * KT * 64;
    conv_frag<<<(total + 255) / 256, 256, 0, stream>>>(s0, k0, s1, k1, s2, k2,
                                                       N, ws + off, KT, total);
  };
  // gates dyn: [z (Wx rows 0:64) | y_prev (Wx rows 576:832) | h (Wh)]
  cv(Wx, 64, Wx + 576 * 2048, 256, Wh, 512, 2048, OFF_WG, 26, 128);
  cv(Wx + 64 * 2048, 512, nil, 0, nil, 0, 2048, OFF_WPH, 16, 128);
  cv(W1, 512, nil, 0, nil, 0, 256, OFF_W1, 16, 16);
  cv(W2, 256, nil, 0, nil, 0, 256, OFF_W2, 8, 16);
  cv(W3, 256, nil, 0, nil, 0, 256, OFF_W3, 8, 16);
  // W4 dyn: [s (rows 512:1024) | y_prev (rows 1280:1536) | y_cur (rows 1024:1280)]
  cv(W4 + 512 * 64, 512, W4 + 1280 * 64, 256, W4 + 1024 * 64, 256, 64, OFF_W4D, 32, 4);
  cv(W4, 512, nil, 0, nil, 0, 64, OFF_W4H, 16, 4);
  // W7 dyn: [s (rows 512:1024) | y_prev (rows 1024:1280)]
  cv(W7 + 512 * 64, 512, W7 + 1024 * 64, 256, nil, 0, 64, OFF_W7D, 24, 4);
  cv(W7, 512, nil, 0, nil, 0, 64, OFF_W7H, 16, 4);
  cv(W5, 64, nil, 0, nil, 0, 64, OFF_W5, 2, 4);
  cv(W6, 64, nil, 0, nil, 0, 64, OFF_W6, 2, 4);
  cv(W8, 64, nil, 0, nil, 0, 64, OFF_W8, 2, 4);
  cv(W9, 64, nil, 0, nil, 0, 64, OFF_W9, 2, 4);

  Params P{h_i, eps_inf, eps_pri, b_lstm,
           b1, b2, b3, b4, b5, b6, b7, b8, b9,
           ws + OFF_WG, ws + OFF_WPH, ws + OFF_W1, ws + OFF_W2, ws + OFF_W3,
           ws + OFF_W4D, ws + OFF_W4H, ws + OFF_W7D, ws + OFF_W7H,
           ws + OFF_W5, ws + OFF_W6, ws + OFF_W8, ws + OFF_W9,
           (float*)d_out};
  vrnn_kernel<<<256, 512, 0, stream>>>(P);
}

// Round 2
// 1835.103 us; speedup vs baseline: 1.3516x; 1.3516x over previous
//
#include <hip/hip_runtime.h>

// Persistent-block VRNN: each block owns 16 batch rows for all 16 timesteps.
// R1: 16 waves/block (1024 thr), 1 block/CU -> 4 waves/SIMD for latency hiding.
// All matmuls via v_mfma_f32_16x16x32_bf16; weights pre-converted to bf16
// MFMA-fragment layout in d_ws so weight streaming is fully coalesced.

typedef __attribute__((ext_vector_type(8))) short short8;
typedef __attribute__((ext_vector_type(4))) float f32x4;

#define Bt 4096
#define Hd 512
#define Fd 256
#define Zd 64
#define Td 16

// workspace offsets in short8 (16B) chunks
#define OFF_WG   0          // gates dyn: K=832 ([z|y_prev|h]), N=2048, KT=26, NT=128
#define OFF_WPH  212992     // h_i gates: K=512, N=2048, KT=16
#define OFF_W1   344064     // K=512 N=256 KT=16 NT=16
#define OFF_W2   360448     // K=256 N=256 KT=8
#define OFF_W3   368640
#define OFF_W4D  376832     // K=1024 ([s|y_prev|y_cur]) N=64 KT=32 NT=4
#define OFF_W4H  385024     // K=512 N=64 KT=16
#define OFF_W7D  389120     // K=768 ([s|y_prev]) N=64 KT=24
#define OFF_W7H  395264     // K=512 N=64 KT=16
#define OFF_W5   399360     // K=64 N=64 KT=2
#define OFF_W6   399872
#define OFF_W8   400384
#define OFF_W9   400896

#define O1 16777216   // mean_all offset in floats
#define O2 20971520   // log_var_all
#define O3 25165824   // z_all

__device__ inline short f2bf(float f) {
  unsigned u = __builtin_bit_cast(unsigned, f);
  unsigned r = (u + 0x7FFFu + ((u >> 16) & 1u)) >> 16;
  return (short)(unsigned short)r;
}
__device__ inline float sigm(float x) { return 1.f / (1.f + __expf(-x)); }
__device__ inline float tanhx(float x) { return 1.f - 2.f / (__expf(2.f * x) + 1.f); }

// Convert f32 weights (row-major [K][N], possibly concatenated from up to 3
// row-ranges) into bf16 MFMA fragment order:
// chunk[((nt*KT+kt)*64+lane)][j] = W[kt*32+(lane>>4)*8+j][nt*16+(lane&15)]
__global__ void conv_frag(const float* s0, int k0, const float* s1, int k1,
                          const float* s2, int k2, int N, short8* dst, int KT,
                          int total) {
  int idx = blockIdx.x * blockDim.x + threadIdx.x;
  if (idx >= total) return;
  int lane = idx & 63;
  int tt = idx >> 6;
  int kt = tt % KT;
  int nt = tt / KT;
  int c = nt * 16 + (lane & 15);
  int kb = kt * 32 + (lane >> 4) * 8;
  short8 v;
#pragma unroll
  for (int j = 0; j < 8; ++j) {
    int kc = kb + j;
    float f;
    if (kc < k0) f = s0[kc * N + c];
    else if (kc < k0 + k1) f = s1[(kc - k0) * N + c];
    else f = s2[(kc - k0 - k1) * N + c];
    v[j] = f2bf(f);
  }
  dst[idx] = v;
}

struct Params {
  const float* h_i; const float* eps_inf; const float* eps_pri;
  const float* b_lstm;
  const float *b1, *b2, *b3, *b4, *b5, *b6, *b7, *b8, *b9;
  const short8 *WG, *WPH, *W1f, *W2f, *W3f, *W4d, *W4h, *W7d, *W7h,
               *W5f, *W6f, *W8f, *W9f;
  float* out;
};

#define A1S 840    // [z(0:64)|y_prev(64:320)|h(320:832)] +8 pad
#define A4S 1032   // [s(0:512)|y_prev(512:768)|y_cur(768:1024)] +8 pad
#define TS  264
#define HZS 72

#define MFMA(a, b, c) __builtin_amdgcn_mfma_f32_16x16x32_bf16((a), (b), (c), 0, 0, 0)

// single-output-tile dense: out tile nt, K = KT*32 from LDS A
template <int KT>
__device__ inline f32x4 dense1(const short* Asrc, int astride, int aoff,
                               const short8* W, const float* bias,
                               int nt, int lane) {
  int lrow = lane >> 4, lcol = lane & 15;
  float b = bias[nt * 16 + lcol];
  f32x4 o = (f32x4){b, b, b, b};
  for (int kt = 0; kt < KT; ++kt) {
    short8 a = *(const short8*)&Asrc[lcol * astride + aoff + kt * 32 + lrow * 8];
    short8 w = W[(nt * KT + kt) * 64 + lane];
    o = MFMA(a, w, o);
  }
  return o;
}

__global__ __launch_bounds__(1024, 1) void vrnn_kernel(Params p) {
  __shared__ short A1[16 * A1S];
  __shared__ short A4[16 * A4S];
  __shared__ short T1[16 * TS];
  __shared__ short T2[16 * TS];
  __shared__ short HZi[16 * HZS];
  __shared__ short HZp[16 * HZS];
  __shared__ float Mi[1024], Li[1024], Mp[1024], Lp[1024];

  const int tid = threadIdx.x;
  const int wave = tid >> 6;
  const int lane = tid & 63;
  const int lrow = lane >> 4;
  const int lcol = lane & 15;
  const int rowbase = blockIdx.x * 16;

  f32x4 base[4][2];   // [gate][j] per-wave gate base (h_i@Wx + b_lstm)
  f32x4 cst[2];       // cell state fragments
  f32x4 base47 = (f32x4){0.f, 0.f, 0.f, 0.f};

  // ---- init: stage h_i (bf16) into A1.h, zero dynamic slots ----
  for (int i = tid; i < 16 * 512; i += 1024) {
    int r = i >> 9, c = i & 511;
    A1[r * A1S + 320 + c] = f2bf(p.h_i[(rowbase + r) * Hd + c]);
  }
  for (int i = tid; i < 16 * 320; i += 1024) {
    int r = i / 320, c = i - r * 320;
    A1[r * A1S + c] = 0;
  }
  for (int i = tid; i < 16 * 256; i += 1024) {
    int r = i >> 8, c = i & 255;
    A4[r * A4S + 512 + c] = 0;
  }
  __syncthreads();

  // ---- precompute base = h_i @ Wx_h + b_lstm ----
#pragma unroll
  for (int g = 0; g < 4; ++g)
#pragma unroll
    for (int j = 0; j < 2; ++j) {
      float b = p.b_lstm[g * 512 + wave * 32 + j * 16 + lcol];
      base[g][j] = (f32x4){b, b, b, b};
    }
  for (int kt = 0; kt < 16; ++kt) {
    short8 a = *(const short8*)&A1[lcol * A1S + 320 + kt * 32 + lrow * 8];
#pragma unroll
    for (int g = 0; g < 4; ++g)
#pragma unroll
      for (int j = 0; j < 2; ++j) {
        int nt = g * 32 + wave * 2 + j;
        short8 w = p.WPH[(nt * 16 + kt) * 64 + lane];
        base[g][j] = MFMA(a, w, base[g][j]);
      }
  }
  // ---- precompute base4 / base7 (waves 0-7) ----
  if (wave < 8) {
    const short8* W = (wave < 4) ? p.W4h : p.W7h;
    const float* bb = (wave < 4) ? p.b4 : p.b7;
    int nt = wave & 3;
    float b = bb[nt * 16 + lcol];
    base47 = (f32x4){b, b, b, b};
    for (int kt = 0; kt < 16; ++kt) {
      short8 a = *(const short8*)&A1[lcol * A1S + 320 + kt * 32 + lrow * 8];
      short8 w = W[(nt * 16 + kt) * 64 + lane];
      base47 = MFMA(a, w, base47);
    }
  }
  __syncthreads();
  // zero h (initial LSTM state)
  for (int i = tid; i < 16 * 512; i += 1024) {
    int r = i >> 9, c = i & 511;
    A1[r * A1S + 320 + c] = 0;
  }
#pragma unroll
  for (int j = 0; j < 2; ++j) cst[j] = (f32x4){0.f, 0.f, 0.f, 0.f};
  __syncthreads();

  // ---- time loop ----
  for (int t = 0; t < Td; ++t) {
    // phase 1: gates = [z|y_prev|h] @ WG + base   (8 MFMA / kt / wave)
    f32x4 acc[4][2];
#pragma unroll
    for (int g = 0; g < 4; ++g)
#pragma unroll
      for (int j = 0; j < 2; ++j) acc[g][j] = base[g][j];
#pragma unroll 2
    for (int kt = 0; kt < 26; ++kt) {
      short8 a = *(const short8*)&A1[lcol * A1S + kt * 32 + lrow * 8];
#pragma unroll
      for (int g = 0; g < 4; ++g)
#pragma unroll
        for (int j = 0; j < 2; ++j) {
          int nt = g * 32 + wave * 2 + j;
          short8 w = p.WG[(nt * 26 + kt) * 64 + lane];
          acc[g][j] = MFMA(a, w, acc[g][j]);
        }
    }
    __syncthreads();

    // phase 2: LSTM pointwise; write h_new -> A1.h, c_new -> A4.s
#pragma unroll
    for (int j = 0; j < 2; ++j) {
#pragma unroll
      for (int r = 0; r < 4; ++r) {
        float iv = sigm(acc[0][j][r]);
        float fv = sigm(acc[1][j][r]);
        float gv = tanhx(acc[2][j][r]);
        float ov = sigm(acc[3][j][r]);
        float cn = fv * cst[j][r] + iv * gv;
        cst[j][r] = cn;
        float hn = ov * tanhx(cn);
        int row = lrow * 4 + r;
        int col = wave * 32 + j * 16 + lcol;
        A1[row * A1S + 320 + col] = f2bf(hn);
        A4[row * A4S + col] = f2bf(cn);
      }
    }
    __syncthreads();

    // phase 3: y = relu(relu(relu(h@W1)@W2)@W3)   (1 out tile / wave)
    {
      f32x4 o = dense1<16>(A1, A1S, 320, p.W1f, p.b1, wave, lane);
#pragma unroll
      for (int r = 0; r < 4; ++r)
        T1[(lrow * 4 + r) * TS + wave * 16 + lcol] = f2bf(fmaxf(o[r], 0.f));
    }
    __syncthreads();
    {
      f32x4 o = dense1<8>(T1, TS, 0, p.W2f, p.b2, wave, lane);
#pragma unroll
      for (int r = 0; r < 4; ++r)
        T2[(lrow * 4 + r) * TS + wave * 16 + lcol] = f2bf(fmaxf(o[r], 0.f));
    }
    __syncthreads();
    {
      f32x4 o = dense1<8>(T2, TS, 0, p.W3f, p.b3, wave, lane);
#pragma unroll
      for (int r = 0; r < 4; ++r) {
        int row = lrow * 4 + r;
        int col = wave * 16 + lcol;
        float v = fmaxf(o[r], 0.f);
        A4[row * A4S + 768 + col] = f2bf(v);
        p.out[(size_t)(rowbase + row) * 4096 + t * 256 + col] = v;
      }
    }
    __syncthreads();

    // phase 4: h_z (inf, waves 0-3, K=1024) / h_z_ (pri, waves 4-7, K=768)
    if (wave < 8) {
      f32x4 hz = base47;
      if (wave < 4) {
        int nt = wave;
        for (int kt = 0; kt < 32; ++kt) {
          short8 a = *(const short8*)&A4[lcol * A4S + kt * 32 + lrow * 8];
          short8 w = p.W4d[(nt * 32 + kt) * 64 + lane];
          hz = MFMA(a, w, hz);
        }
#pragma unroll
        for (int r = 0; r < 4; ++r)
          HZi[(lrow * 4 + r) * HZS + nt * 16 + lcol] = f2bf(fmaxf(hz[r], 0.f));
      } else {
        int nt = wave - 4;
        for (int kt = 0; kt < 24; ++kt) {
          short8 a = *(const short8*)&A4[lcol * A4S + kt * 32 + lrow * 8];
          short8 w = p.W7d[(nt * 24 + kt) * 64 + lane];
          hz = MFMA(a, w, hz);
        }
#pragma unroll
        for (int r = 0; r < 4; ++r)
          HZp[(lrow * 4 + r) * HZS + nt * 16 + lcol] = f2bf(fmaxf(hz[r], 0.f));
      }
    }
    __syncthreads();

    // phase 5: mean/log_var heads (W5,W6 inf; W8,W9 pri), K=64, 1 tile/wave
    {
      int m = wave >> 2, q = wave & 3;
      const short8* W = (m == 0) ? p.W5f : (m == 1) ? p.W6f : (m == 2) ? p.W8f : p.W9f;
      const float* bb = (m == 0) ? p.b5 : (m == 1) ? p.b6 : (m == 2) ? p.b8 : p.b9;
      const short* As = (m < 2) ? HZi : HZp;
      float b = bb[q * 16 + lcol];
      f32x4 o = (f32x4){b, b, b, b};
#pragma unroll
      for (int kt = 0; kt < 2; ++kt) {
        short8 a = *(const short8*)&As[lcol * HZS + kt * 32 + lrow * 8];
        short8 w = W[(q * 2 + kt) * 64 + lane];
        o = MFMA(a, w, o);
      }
#pragma unroll
      for (int r = 0; r < 4; ++r) {
        int row = lrow * 4 + r;
        int col = q * 16 + lcol;
        float v = fmaxf(o[r], 0.f);
        size_t gb = (size_t)(rowbase + row) * 1024 + t * 64;
        if (m == 0) {
          Mi[row * 64 + col] = v; p.out[O1 + gb + col] = v;
        } else if (m == 1) {
          Li[row * 64 + col] = v; p.out[O2 + gb + col] = v;
        } else if (m == 2) {
          Mp[row * 64 + col] = v;
        } else {
          Lp[row * 64 + col] = v;
        }
      }
    }
    __syncthreads();

    // phase 6: z sampling + output + state shuffles
    {
      int e = tid;  // 1024 threads, 1024 elements
      int row = e >> 6, col = e & 63;
      int b = rowbase + row;
      float ei = p.eps_inf[((size_t)t * Bt + b) * 64 + col];
      float ep = p.eps_pri[((size_t)t * Bt + b) * 64 + col];
      float zi = Mi[e] + ei * sqrtf(__expf(Li[e]));
      float zp = Mp[e] + ep * sqrtf(__expf(Lp[e]));
      p.out[O3 + ((size_t)(t * 2 + 0) * Bt + b) * 64 + col] = zi;
      p.out[O3 + ((size_t)(t * 2 + 1) * Bt + b) * 64 + col] = zp;
      A1[row * A1S + col] = f2bf(zi);   // z state for next step
    }
    for (int i = tid; i < 16 * 256; i += 1024) {
      int r = i >> 8, c = i & 255;
      short v = A4[r * A4S + 768 + c];  // y_cur
      A1[r * A1S + 64 + c] = v;         // -> A1.y_prev
      A4[r * A4S + 512 + c] = v;        // -> A4.y_prev
    }
    __syncthreads();
  }
}

extern "C" void kernel_launch(void* const* d_in, const int* in_sizes, int n_in,
                              void* d_out, int out_size, void* d_ws, size_t ws_size,
                              hipStream_t stream) {
  const float* h_i     = (const float*)d_in[0];
  const float* eps_inf = (const float*)d_in[1];
  const float* eps_pri = (const float*)d_in[2];
  const float* Wx      = (const float*)d_in[3];
  const float* Wh      = (const float*)d_in[4];
  const float* b_lstm  = (const float*)d_in[5];
  const float* W1 = (const float*)d_in[6];  const float* b1 = (const float*)d_in[7];
  const float* W2 = (const float*)d_in[8];  const float* b2 = (const float*)d_in[9];
  const float* W3 = (const float*)d_in[10]; const float* b3 = (const float*)d_in[11];
  const float* W4 = (const float*)d_in[12]; const float* b4 = (const float*)d_in[13];
  const float* W5 = (const float*)d_in[14]; const float* b5 = (const float*)d_in[15];
  const float* W6 = (const float*)d_in[16]; const float* b6 = (const float*)d_in[17];
  const float* W7 = (const float*)d_in[18]; const float* b7 = (const float*)d_in[19];
  const float* W8 = (const float*)d_in[20]; const float* b8 = (const float*)d_in[21];
  const float* W9 = (const float*)d_in[22]; const float* b9 = (const float*)d_in[23];
  short8* ws = (short8*)d_ws;
  const float* nil = nullptr;

  auto cv = [&](const float* s0, int k0, const float* s1, int k1,
                const float* s2, int k2, int N, int off, int KT, int NT) {
    int total = NT * KT * 64;
    conv_frag<<<(total + 255) / 256, 256, 0, stream>>>(s0, k0, s1, k1, s2, k2,
                                                       N, ws + off, KT, total);
  };
  // gates dyn: [z (Wx rows 0:64) | y_prev (Wx rows 576:832) | h (Wh)]
  cv(Wx, 64, Wx + 576 * 2048, 256, Wh, 512, 2048, OFF_WG, 26, 128);
  cv(Wx + 64 * 2048, 512, nil, 0, nil, 0, 2048, OFF_WPH, 16, 128);
  cv(W1, 512, nil, 0, nil, 0, 256, OFF_W1, 16, 16);
  cv(W2, 256, nil, 0, nil, 0, 256, OFF_W2, 8, 16);
  cv(W3, 256, nil, 0, nil, 0, 256, OFF_W3, 8, 16);
  // W4 dyn: [s (rows 512:1024) | y_prev (rows 1280:1536) | y_cur (rows 1024:1280)]
  cv(W4 + 512 * 64, 512, W4 + 1280 * 64, 256, W4 + 1024 * 64, 256, 64, OFF_W4D, 32, 4);
  cv(W4, 512, nil, 0, nil, 0, 64, OFF_W4H, 16, 4);
  // W7 dyn: [s (rows 512:1024) | y_prev (rows 1024:1280)]
  cv(W7 + 512 * 64, 512, W7 + 1024 * 64, 256, nil, 0, 64, OFF_W7D, 24, 4);
  cv(W7, 512, nil, 0, nil, 0, 64, OFF_W7H, 16, 4);
  cv(W5, 64, nil, 0, nil, 0, 64, OFF_W5, 2, 4);
  cv(W6, 64, nil, 0, nil, 0, 64, OFF_W6, 2, 4);
  cv(W8, 64, nil, 0, nil, 0, 64, OFF_W8, 2, 4);
  cv(W9, 64, nil, 0, nil, 0, 64, OFF_W9, 2, 4);

  Params P{h_i, eps_inf, eps_pri, b_lstm,
           b1, b2, b3, b4, b5, b6, b7, b8, b9,
           ws + OFF_WG, ws + OFF_WPH, ws + OFF_W1, ws + OFF_W2, ws + OFF_W3,
           ws + OFF_W4D, ws + OFF_W4H, ws + OFF_W7D, ws + OFF_W7H,
           ws + OFF_W5, ws + OFF_W6, ws + OFF_W8, ws + OFF_W9,
           (float*)d_out};
  vrnn_kernel<<<256, 1024, 0, stream>>>(P);
}